// Round 10
// baseline (177.700 us; speedup 1.0000x reference)
//
#include <hip/hip_runtime.h>
#include <stdint.h>

#define B_SZ 1024
#define H_SZ 16384
#define SD   32
#define HID  64
#define G_SZ 10
#define K_SZ 4
#define A_SZ 8
#define VA   80         // G*A
#define NC   16         // chunks (Pacc = 21 MB)

typedef float f32x4  __attribute__((ext_vector_type(4)));
typedef short bf16x8 __attribute__((ext_vector_type(8)));

__device__ inline short f2bf(float a) {
    unsigned u = __float_as_uint(a);
    return (short)((u + 0x7FFFu + ((u >> 16) & 1u)) >> 16);
}
__device__ inline void split_bf(float v, short& hi, short& lo) {
    hi = f2bf(v);
    lo = f2bf(v - __uint_as_float(((unsigned)(unsigned short)hi) << 16));
}
// HW packed f32->bf16 (RTNE — bit-identical to the manual pack, 1 instr).
__device__ inline int cvt_pk_bf16(float a, float b) {
    int r;
    asm("v_cvt_pk_bf16_f32 %0, %1, %2" : "=v"(r) : "v"(a), "v"(b));
    return r;
}
// hi/lo split of a PAIR via cvt_pk: bit-identical to split_bf elementwise.
__device__ inline void split2(float f0, float f1, int& hi, int& lo) {
    hi = cvt_pk_bf16(f0, f1);
    float r0 = f0 - __uint_as_float((unsigned)hi << 16);
    float r1 = f1 - __uint_as_float((unsigned)hi & 0xFFFF0000u);
    lo = cvt_pk_bf16(r0, r1);
}

// ---------------------------------------------------------------------------
// Kernel 0: pre-split weights to bf16 hi/lo in MFMA-FRAGMENT order.
// ---------------------------------------------------------------------------
__global__ __launch_bounds__(256) void k_prep(
    const float* __restrict__ W0, const float* __restrict__ W1,
    const float* __restrict__ W2,
    short* __restrict__ w0h, short* __restrict__ w0l,
    short* __restrict__ w1h, short* __restrict__ w1l,
    short* __restrict__ w2h, short* __restrict__ w2l)
{
    int idx = blockIdx.x * 256 + threadIdx.x;    // 40960 total
    short hh, ll;
    if (idx < 8192) {                            // w0f
        int k = idx >> 11, r = idx & 2047;
        int i = r >> 6, jj = r & 63;
        int tt = jj >> 4, l15 = jj & 15;
        int quad = (i >> 3) & 3, e = i & 7;
        split_bf(W0[k * 2048 + i * 64 + jj], hh, ll);
        int dst = k * 2048 + tt * 512 + (quad * 16 + l15) * 8 + e;
        w0h[dst] = hh; w0l[dst] = ll;
    } else if (idx < 24576) {                    // w1f
        int d = idx - 8192;
        int k = d >> 12, r = d & 4095;
        int i = r >> 6, jj = r & 63;
        int kb = i >> 5, quad = (i >> 3) & 3, e = i & 7;
        int tt = jj >> 4, l15 = jj & 15;
        split_bf(W1[k * 4096 + i * 64 + jj], hh, ll);
        int dst = k * 4096 + tt * 1024 + kb * 512 + (quad * 16 + l15) * 8 + e;
        w1h[dst] = hh; w1l[dst] = ll;
    } else if (idx < 40960) {                    // w2f
        int d = idx - 24576;
        int k = d >> 12, r = d & 4095;
        int i = r >> 6, jj = r & 63;
        int kb = i >> 5, quad = (i >> 3) & 3, e = i & 7;
        int tt = jj >> 4, l15 = jj & 15;
        split_bf(W2[k * 4096 + i * 64 + jj], hh, ll);
        int dst = k * 4096 + tt * 1024 + kb * 512 + (quad * 16 + l15) * 8 + e;
        w2h[dst] = hh; w2l[dst] = ll;
    }
}

// ---------------------------------------------------------------------------
// Kernel 1: per-k 3-layer MLP encoders (R8 structure, unchanged).
// ---------------------------------------------------------------------------
__global__ __launch_bounds__(256, 3) void k_encode(
    const float* __restrict__ state, const float* __restrict__ hist,
    const float* __restrict__ act,
    const short* __restrict__ w0fh, const short* __restrict__ w0fl,
    const short* __restrict__ w1fh, const short* __restrict__ w1fl,
    const short* __restrict__ w2fh, const short* __restrict__ w2fl,
    const float* __restrict__ b0, const float* __restrict__ b1,
    const float* __restrict__ b2,
    short* __restrict__ enc_s_h, short* __restrict__ enc_s_l,
    short* __restrict__ kf_h, short* __restrict__ kf_l,
    short* __restrict__ vf_h, short* __restrict__ vf_l)
{
    __shared__ __align__(16) short smem[18432];   // 36864 B
    const int bid = blockIdx.x;
    const int t = threadIdx.x;

    if (bid >= 1088) {
        // ---- V transpose role: tile of 64 h rows ----
        short* tile_h = smem;                 // [64][84]
        short* tile_l = smem + 5376;
        const int h0 = (bid - 1088) * 64;
        #pragma unroll
        for (int i = 0; i < 10; ++i) {
            int idx2 = 2 * (t + i * 256);     // 0..5118, even
            float2 v = *(const float2*)(act + (size_t)h0 * VA + idx2);
            int h = idx2 / 80, c = idx2 - h * 80;
            int hi, lo; split2(v.x, v.y, hi, lo);
            *(int*)(tile_h + h * 84 + c) = hi;
            *(int*)(tile_l + h * 84 + c) = lo;
        }
        __syncthreads();
        #pragma unroll
        for (int i = 0; i < 3; ++i) {
            int jj = t + i * 256;             // 0..639 used
            if (jj < 640) {
                int va = jj >> 3, hb = jj & 7;
                union { short s[8]; uint4 v; } uh, ul;
                #pragma unroll
                for (int uu = 0; uu < 8; ++uu) {
                    uh.s[uu] = tile_h[(hb * 8 + uu) * 84 + va];
                    ul.s[uu] = tile_l[(hb * 8 + uu) * 84 + va];
                }
                int vtile = (h0 >> 5) + (hb >> 2);
                int lanep = ((hb & 3) << 4) | (va & 15);
                size_t a = (size_t)vtile * 2560 + (va >> 4) * 512 + lanep * 8;
                *(uint4*)(vf_h + a) = uh.v;
                *(uint4*)(vf_l + a) = ul.v;
            }
        }
        return;
    }

    // ---- encode role ----
    const int k = bid / 272;
    const int tl = bid % 272;
    const bool is_state = (tl < 16);
    const float qscale = is_state ? 1.44269504f : 1.0f;   // log2(e) into Q
    const float* X = is_state ? state + (size_t)tl * 64 * SD
                              : hist + (size_t)(tl - 16) * 64 * SD;
    short* dst_h = enc_s_h + ((size_t)k * B_SZ + tl * 64) * HID;
    short* dst_l = enc_s_l + ((size_t)k * B_SZ + tl * 64) * HID;

    // LDS (shorts), lifetime reuse: R1 = xt -> hb2, R2 = hb1 -> ot.
    short* xt_h  = smem;            // [64][40]
    short* xt_l  = smem + 2560;
    short* hb2_h = smem;            // [64][72] (L2 out, L3 in)
    short* hb2_l = smem + 4608;
    short* hb1_h = smem + 9216;     // [64][72] (L1 out, L2 in)
    short* hb1_l = smem + 13824;
    short* ot_h  = smem + 9216;     // L3 out staging (hb1 dead)
    short* ot_l  = smem + 13824;

    { // stage x tile (64x32 fp32 -> hi/lo), pairwise
        int r = t >> 2, c0 = (t & 3) * 8;
        const float* src = X + r * SD + c0;
        #pragma unroll
        for (int u = 0; u < 4; ++u) {
            float2 v = *(const float2*)(src + 2 * u);
            int hi, lo; split2(v.x, v.y, hi, lo);
            *(int*)(xt_h + r * 40 + c0 + 2 * u) = hi;
            *(int*)(xt_l + r * 40 + c0 + 2 * u) = lo;
        }
    }
    __syncthreads();

    const int w = t >> 6, l15 = t & 15, quad = (t >> 4) & 3, lane = t & 63;
    const f32x4 fz = {0.f, 0.f, 0.f, 0.f};
    const int row0 = w * 16 + quad * 4;

    // Layer 1 (K=32)
    {
        bf16x8 xa_h = *(const bf16x8*)(xt_h + (w * 16 + l15) * 40 + quad * 8);
        bf16x8 xa_l = *(const bf16x8*)(xt_l + (w * 16 + l15) * 40 + quad * 8);
        const float* b0k = b0 + k * HID;
        const short* wbh = w0fh + k * 2048 + lane * 8;
        const short* wbl = w0fl + k * 2048 + lane * 8;
        #pragma unroll
        for (int tt = 0; tt < 4; ++tt) {
            bf16x8 wf_h = *(const bf16x8*)(wbh + tt * 512);
            bf16x8 wf_l = *(const bf16x8*)(wbl + tt * 512);
            f32x4 c = __builtin_amdgcn_mfma_f32_16x16x32_bf16(xa_h, wf_h, fz, 0, 0, 0);
            c = __builtin_amdgcn_mfma_f32_16x16x32_bf16(xa_l, wf_h, c, 0, 0, 0);
            c = __builtin_amdgcn_mfma_f32_16x16x32_bf16(xa_h, wf_l, c, 0, 0, 0);
            float bias = b0k[l15 + 16 * tt];
            float f0 = fmaxf(c[0] + bias, 0.f), f1 = fmaxf(c[1] + bias, 0.f);
            float f2 = fmaxf(c[2] + bias, 0.f), f3 = fmaxf(c[3] + bias, 0.f);
            int h01, l01, h23, l23;
            split2(f0, f1, h01, l01); split2(f2, f3, h23, l23);
            int cc = l15 + 16 * tt;
            hb1_h[(row0    ) * 72 + cc] = (short)h01;
            hb1_h[(row0 + 1) * 72 + cc] = (short)(h01 >> 16);
            hb1_h[(row0 + 2) * 72 + cc] = (short)h23;
            hb1_h[(row0 + 3) * 72 + cc] = (short)(h23 >> 16);
            hb1_l[(row0    ) * 72 + cc] = (short)l01;
            hb1_l[(row0 + 1) * 72 + cc] = (short)(l01 >> 16);
            hb1_l[(row0 + 2) * 72 + cc] = (short)l23;
            hb1_l[(row0 + 3) * 72 + cc] = (short)(l23 >> 16);
        }
    }
    __syncthreads();
    // Layer 2 (K=64)
    {
        bf16x8 ha0_h = *(const bf16x8*)(hb1_h + (w * 16 + l15) * 72 + quad * 8);
        bf16x8 ha0_l = *(const bf16x8*)(hb1_l + (w * 16 + l15) * 72 + quad * 8);
        bf16x8 ha1_h = *(const bf16x8*)(hb1_h + (w * 16 + l15) * 72 + 32 + quad * 8);
        bf16x8 ha1_l = *(const bf16x8*)(hb1_l + (w * 16 + l15) * 72 + 32 + quad * 8);
        const float* b1k = b1 + k * HID;
        const short* wbh = w1fh + k * 4096 + lane * 8;
        const short* wbl = w1fl + k * 4096 + lane * 8;
        #pragma unroll
        for (int tt = 0; tt < 4; ++tt) {
            bf16x8 wfa_h = *(const bf16x8*)(wbh + tt * 1024);
            bf16x8 wfb_h = *(const bf16x8*)(wbh + tt * 1024 + 512);
            bf16x8 wfa_l = *(const bf16x8*)(wbl + tt * 1024);
            bf16x8 wfb_l = *(const bf16x8*)(wbl + tt * 1024 + 512);
            f32x4 c = __builtin_amdgcn_mfma_f32_16x16x32_bf16(ha0_h, wfa_h, fz, 0, 0, 0);
            c = __builtin_amdgcn_mfma_f32_16x16x32_bf16(ha1_h, wfb_h, c, 0, 0, 0);
            c = __builtin_amdgcn_mfma_f32_16x16x32_bf16(ha0_l, wfa_h, c, 0, 0, 0);
            c = __builtin_amdgcn_mfma_f32_16x16x32_bf16(ha1_l, wfb_h, c, 0, 0, 0);
            c = __builtin_amdgcn_mfma_f32_16x16x32_bf16(ha0_h, wfa_l, c, 0, 0, 0);
            c = __builtin_amdgcn_mfma_f32_16x16x32_bf16(ha1_h, wfb_l, c, 0, 0, 0);
            float bias = b1k[l15 + 16 * tt];
            float f0 = fmaxf(c[0] + bias, 0.f), f1 = fmaxf(c[1] + bias, 0.f);
            float f2 = fmaxf(c[2] + bias, 0.f), f3 = fmaxf(c[3] + bias, 0.f);
            int h01, l01, h23, l23;
            split2(f0, f1, h01, l01); split2(f2, f3, h23, l23);
            int cc = l15 + 16 * tt;
            hb2_h[(row0    ) * 72 + cc] = (short)h01;
            hb2_h[(row0 + 1) * 72 + cc] = (short)(h01 >> 16);
            hb2_h[(row0 + 2) * 72 + cc] = (short)h23;
            hb2_h[(row0 + 3) * 72 + cc] = (short)(h23 >> 16);
            hb2_l[(row0    ) * 72 + cc] = (short)l01;
            hb2_l[(row0 + 1) * 72 + cc] = (short)(l01 >> 16);
            hb2_l[(row0 + 2) * 72 + cc] = (short)l23;
            hb2_l[(row0 + 3) * 72 + cc] = (short)(l23 >> 16);
        }
    }
    __syncthreads();
    // Layer 3 (K=64): hb2 -> ot
    {
        bf16x8 ha0_h = *(const bf16x8*)(hb2_h + (w * 16 + l15) * 72 + quad * 8);
        bf16x8 ha0_l = *(const bf16x8*)(hb2_l + (w * 16 + l15) * 72 + quad * 8);
        bf16x8 ha1_h = *(const bf16x8*)(hb2_h + (w * 16 + l15) * 72 + 32 + quad * 8);
        bf16x8 ha1_l = *(const bf16x8*)(hb2_l + (w * 16 + l15) * 72 + 32 + quad * 8);
        const float* b2k = b2 + k * HID;
        const short* wbh = w2fh + k * 4096 + lane * 8;
        const short* wbl = w2fl + k * 4096 + lane * 8;
        #pragma unroll
        for (int tt = 0; tt < 4; ++tt) {
            bf16x8 wfa_h = *(const bf16x8*)(wbh + tt * 1024);
            bf16x8 wfb_h = *(const bf16x8*)(wbh + tt * 1024 + 512);
            bf16x8 wfa_l = *(const bf16x8*)(wbl + tt * 1024);
            bf16x8 wfb_l = *(const bf16x8*)(wbl + tt * 1024 + 512);
            f32x4 c = __builtin_amdgcn_mfma_f32_16x16x32_bf16(ha0_h, wfa_h, fz, 0, 0, 0);
            c = __builtin_amdgcn_mfma_f32_16x16x32_bf16(ha1_h, wfb_h, c, 0, 0, 0);
            c = __builtin_amdgcn_mfma_f32_16x16x32_bf16(ha0_l, wfa_h, c, 0, 0, 0);
            c = __builtin_amdgcn_mfma_f32_16x16x32_bf16(ha1_l, wfb_h, c, 0, 0, 0);
            c = __builtin_amdgcn_mfma_f32_16x16x32_bf16(ha0_h, wfa_l, c, 0, 0, 0);
            c = __builtin_amdgcn_mfma_f32_16x16x32_bf16(ha1_h, wfb_l, c, 0, 0, 0);
            float bias = b2k[l15 + 16 * tt];
            float f0 = fmaxf(c[0] + bias, 0.f) * qscale;
            float f1 = fmaxf(c[1] + bias, 0.f) * qscale;
            float f2 = fmaxf(c[2] + bias, 0.f) * qscale;
            float f3 = fmaxf(c[3] + bias, 0.f) * qscale;
            int h01, l01, h23, l23;
            split2(f0, f1, h01, l01); split2(f2, f3, h23, l23);
            int cc = l15 + 16 * tt;
            ot_h[(row0    ) * 72 + cc] = (short)h01;
            ot_h[(row0 + 1) * 72 + cc] = (short)(h01 >> 16);
            ot_h[(row0 + 2) * 72 + cc] = (short)h23;
            ot_h[(row0 + 3) * 72 + cc] = (short)(h23 >> 16);
            ot_l[(row0    ) * 72 + cc] = (short)l01;
            ot_l[(row0 + 1) * 72 + cc] = (short)(l01 >> 16);
            ot_l[(row0 + 2) * 72 + cc] = (short)l23;
            ot_l[(row0 + 3) * 72 + cc] = (short)(l23 >> 16);
        }
    }
    __syncthreads();
    // Coalesced global write: 512 uint4-pairs, 2 per thread.
    if (is_state) {
        #pragma unroll
        for (int u = 0; u < 2; ++u) {
            int id = t * 2 + u;               // 0..511
            int row = id >> 3, c0 = (id & 7) * 8;
            *(uint4*)(dst_h + row * HID + c0) = *(const uint4*)(ot_h + row * 72 + c0);
            *(uint4*)(dst_l + row * HID + c0) = *(const uint4*)(ot_l + row * 72 + c0);
        }
    } else {
        const int ktbase = k * 512 + (tl - 16) * 2;
        #pragma unroll
        for (int u = 0; u < 2; ++u) {
            int id = t * 2 + u;               // 0..511
            int kt2 = id >> 8;                // 0..1
            int f2 = (id >> 6) & 3;
            int lanep = id & 63;
            int hl = kt2 * 32 + ((f2 >> 1) & 1) * 16 + (lanep & 15);
            int c0 = (f2 & 1) * 32 + ((lanep >> 4) & 3) * 8;
            size_t a = (size_t)(ktbase + kt2) * 2048 + f2 * 512 + (size_t)lanep * 8;
            *(uint4*)(kf_h + a) = *(const uint4*)(ot_h + hl * 72 + c0);
            *(uint4*)(kf_l + a) = *(const uint4*)(ot_l + hl * 72 + c0);
        }
    }
}

// ---------------------------------------------------------------------------
// Kernel 2: flash attention partials — WAVE-GRANULAR (64-thread blocks).
// R9 lesson: 4-wave blocks wasted 4 of 12 reg-limited wave slots/CU and the
// grid capped waves at 8/CU; R8 vs R9 showed dur invariant because BOTH ran
// 8 waves/CU. Now: 1 wave = 1 block = 16 queries (one sub). Total MFMA is
// unchanged (QK 12 + PV 10 per 16q = same per-q rate); per-wave regs drop
// ~45 -> ~4 waves/SIMD packable; grid 4096 waves = 16 waves/CU (2x).
// Register K double-buffer + split V issue retained (R6 pipeline).
// ---------------------------------------------------------------------------
template<int NCt>
__global__ __launch_bounds__(64, 2) void k_flash(
    const short* __restrict__ enc_s_h, const short* __restrict__ enc_s_l,
    const short* __restrict__ kf_h, const short* __restrict__ kf_l,
    const short* __restrict__ vf_h, const short* __restrict__ vf_l,
    float* __restrict__ Pm, float* __restrict__ Pl, float* __restrict__ Pacc)
{
    constexpr int CHt = H_SZ / NCt;
    constexpr int NT = CHt / 32;
    static_assert(NT % 2 == 0, "NT must be even for 2x unroll");

    const int bid = blockIdx.x;                 // [0, 4096)
    // XCD-group swizzle (bijective): the 64 q-tiles of a (k,chunk) share
    // bid%8 -> same XCD under round-robin dispatch (K/V chunk ~600 KB, L2).
    const int r8 = bid & 7, j = bid >> 3;       // j in [0,512)
    const int qt = j & 63, grp = j >> 6;        // qt: q-tile, grp in [0,8)
    const int idx = grp * 8 + r8;               // [0,64)
    const int k = idx / NCt, chunk = idx % NCt;
    const int t = threadIdx.x;                  // lane 0..63
    const int l15 = t & 15, quad = (t >> 4) & 3;
    const int q0 = qt * 16;
    const f32x4 fz = {0.f, 0.f, 0.f, 0.f};

    bf16x8 qh[2], ql[2];
    #pragma unroll
    for (int kb = 0; kb < 2; ++kb) {
        size_t off = ((size_t)k * B_SZ + q0 + l15) * HID + kb * 32 + quad * 8;
        qh[kb] = *(const bf16x8*)(enc_s_h + off);
        ql[kb] = *(const bf16x8*)(enc_s_l + off);
    }

    f32x4 acc[5];
    #pragma unroll
    for (int tt = 0; tt < 5; ++tt) acc[tt] = fz;
    float mrun = -__builtin_inff();
    float lrun = 0.f;

    const int tile0 = chunk * NT;
    const short* kbh = kf_h + ((size_t)(k * 512 + tile0)) * 2048 + t * 8;
    const short* kbl = kf_l + ((size_t)(k * 512 + tile0)) * 2048 + t * 8;
    const short* vbh = vf_h + (size_t)tile0 * 2560 + t * 8;
    const short* vbl = vf_l + (size_t)tile0 * 2560 + t * 8;

    // kc/kn: [0..3] = hi frags, [4..7] = lo frags (static indices only).
    bf16x8 kA[8], kB[8];
    #pragma unroll
    for (int f = 0; f < 4; ++f) {
        kA[f]     = *(const bf16x8*)(kbh + f * 512);
        kA[4 + f] = *(const bf16x8*)(kbl + f * 512);
    }

    auto body = [&](bf16x8 (&kc)[8], bf16x8 (&kn)[8], int it) {
        bf16x8 vh[5], vl[5];
        const short* vph = vbh + (size_t)it * 2560;
        const short* vpl = vbl + (size_t)it * 2560;
        #pragma unroll
        for (int tt = 0; tt < 3; ++tt) {
            vh[tt] = *(const bf16x8*)(vph + tt * 512);
            vl[tt] = *(const bf16x8*)(vpl + tt * 512);
        }
        if (it + 1 < NT) {
            const short* nph = kbh + (size_t)(it + 1) * 2048;
            const short* npl = kbl + (size_t)(it + 1) * 2048;
            #pragma unroll
            for (int f = 0; f < 4; ++f) {
                kn[f]     = *(const bf16x8*)(nph + f * 512);
                kn[4 + f] = *(const bf16x8*)(npl + f * 512);
            }
        }

        // QK on resident kc (single sub of 16 q)
        f32x4 slo, shi;
        __builtin_amdgcn_s_setprio(1);
        {
            f32x4 c = __builtin_amdgcn_mfma_f32_16x16x32_bf16(kc[0], qh[0], fz, 0, 0, 0);
            c = __builtin_amdgcn_mfma_f32_16x16x32_bf16(kc[1], qh[1], c, 0, 0, 0);
            c = __builtin_amdgcn_mfma_f32_16x16x32_bf16(kc[4], qh[0], c, 0, 0, 0);
            c = __builtin_amdgcn_mfma_f32_16x16x32_bf16(kc[5], qh[1], c, 0, 0, 0);
            c = __builtin_amdgcn_mfma_f32_16x16x32_bf16(kc[0], ql[0], c, 0, 0, 0);
            c = __builtin_amdgcn_mfma_f32_16x16x32_bf16(kc[1], ql[1], c, 0, 0, 0);
            slo = c;
            f32x4 d = __builtin_amdgcn_mfma_f32_16x16x32_bf16(kc[2], qh[0], fz, 0, 0, 0);
            d = __builtin_amdgcn_mfma_f32_16x16x32_bf16(kc[3], qh[1], d, 0, 0, 0);
            d = __builtin_amdgcn_mfma_f32_16x16x32_bf16(kc[6], qh[0], d, 0, 0, 0);
            d = __builtin_amdgcn_mfma_f32_16x16x32_bf16(kc[7], qh[1], d, 0, 0, 0);
            d = __builtin_amdgcn_mfma_f32_16x16x32_bf16(kc[2], ql[0], d, 0, 0, 0);
            d = __builtin_amdgcn_mfma_f32_16x16x32_bf16(kc[3], ql[1], d, 0, 0, 0);
            shi = d;
        }
        __builtin_amdgcn_s_setprio(0);

        #pragma unroll
        for (int tt = 3; tt < 5; ++tt) {
            vh[tt] = *(const bf16x8*)(vph + tt * 512);
            vl[tt] = *(const bf16x8*)(vpl + tt * 512);
        }

        // softmax (S in log2 units; Q pre-scaled by log2e at encode)
        bf16x8 pfv;
        {
            float a3 = fmaxf(fmaxf(slo[0], slo[1]), slo[2]);
            float b3 = fmaxf(fmaxf(slo[3], shi[0]), shi[1]);
            float c3 = fmaxf(fmaxf(shi[2], shi[3]), a3);
            float tm = fmaxf(b3, c3);
            tm = fmaxf(tm, __shfl_xor(tm, 16));
            tm = fmaxf(tm, __shfl_xor(tm, 32));
            if (__any(tm > mrun)) {
                float mnew = fmaxf(mrun, tm);
                float alpha = exp2f(mrun - mnew);
                lrun *= alpha;
                #pragma unroll
                for (int tt = 0; tt < 5; ++tt) acc[tt] = acc[tt] * alpha;
                mrun = mnew;
            }
            float m = mrun;
            float p0 = exp2f(slo[0] - m), p1 = exp2f(slo[1] - m);
            float p2 = exp2f(slo[2] - m), p3 = exp2f(slo[3] - m);
            float p4 = exp2f(shi[0] - m), p5 = exp2f(shi[1] - m);
            float p6 = exp2f(shi[2] - m), p7 = exp2f(shi[3] - m);
            float ps = (p0 + p1) + (p2 + p3) + (p4 + p5) + (p6 + p7);
            ps += __shfl_xor(ps, 16);
            ps += __shfl_xor(ps, 32);
            lrun += ps;

            int plo01 = cvt_pk_bf16(p0, p1), plo23 = cvt_pk_bf16(p2, p3);
            int phi01 = cvt_pk_bf16(p4, p5), phi23 = cvt_pk_bf16(p6, p7);
            union { int i[4]; bf16x8 v; } pf;
            #pragma unroll
            for (int jj = 0; jj < 4; ++jj) {
                int src = (((2 * quad + (jj >> 1)) & 3) << 4) + l15;
                int glo = __shfl((jj & 1) ? plo23 : plo01, src);
                int ghi = __shfl((jj & 1) ? phi23 : phi01, src);
                pf.i[jj] = (quad >= 2) ? ghi : glo;
            }
            pfv = pf.v;
        }

        // PV: V in flight since iteration start
        __builtin_amdgcn_s_setprio(1);
        #pragma unroll
        for (int tt = 0; tt < 5; ++tt) {
            acc[tt] = __builtin_amdgcn_mfma_f32_16x16x32_bf16(vh[tt], pfv, acc[tt], 0, 0, 0);
            acc[tt] = __builtin_amdgcn_mfma_f32_16x16x32_bf16(vl[tt], pfv, acc[tt], 0, 0, 0);
        }
        __builtin_amdgcn_s_setprio(0);
    };

    for (int ii = 0; ii < NT; ii += 2) {
        body(kA, kB, ii);
        body(kB, kA, ii + 1);
    }

    const int q = k * B_SZ + q0 + l15;
    if (quad == 0) {
        Pm[chunk * 4096 + q] = mrun;
        Pl[chunk * 4096 + q] = lrun;
    }
    #pragma unroll
    for (int tt = 0; tt < 5; ++tt)
        #pragma unroll
        for (int r = 0; r < 4; ++r) {
            int va = tt * 16 + quad * 4 + r;
            Pacc[((size_t)chunk * VA + va) * 4096 + q] = acc[tt][r];
        }
}

// ---------------------------------------------------------------------------
// Kernel 3: FUSED combine (R9 version, unchanged): per thread one (b,va),
// all 4 k's combined + softmax(assignment) mix.
// ---------------------------------------------------------------------------
__global__ __launch_bounds__(256) void k_reduce(
    const float* __restrict__ Pm, const float* __restrict__ Pl,
    const float* __restrict__ Pacc, const float* __restrict__ assign,
    float* __restrict__ out)
{
    const int bid = blockIdx.x;
    const int qb = bid / 20, vcg = bid - qb * 20;
    const int t = threadIdx.x;
    const int b = qb * 64 + (t & 63);
    const int va = vcg * 4 + (t >> 6);
    const int g = va >> 3;

    float mc[K_SZ][NC];
    float M[K_SZ] = {-__builtin_inff(), -__builtin_inff(),
                     -__builtin_inff(), -__builtin_inff()};
    #pragma unroll
    for (int c = 0; c < NC; ++c)
        #pragma unroll
        for (int k = 0; k < K_SZ; ++k) {
            float m = Pm[c * 4096 + k * B_SZ + b];
            mc[k][c] = m;
            M[k] = fmaxf(M[k], m);
        }
    float L[K_SZ] = {0.f, 0.f, 0.f, 0.f};
    #pragma unroll
    for (int c = 0; c < NC; ++c)
        #pragma unroll
        for (int k = 0; k < K_SZ; ++k) {
            float wv = exp2f(mc[k][c] - M[k]);
            mc[k][c] = wv;
            L[k] += wv * Pl[c * 4096 + k * B_SZ + b];
        }
    float o[K_SZ] = {0.f, 0.f, 0.f, 0.f};
    #pragma unroll
    for (int c = 0; c < NC; ++c)
        #pragma unroll
        for (int k = 0; k < K_SZ; ++k)
            o[k] += mc[k][c] * Pacc[((size_t)(c * VA + va)) * 4096 + k * B_SZ + b];

    float a0 = assign[g * K_SZ + 0], a1 = assign[g * K_SZ + 1];
    float a2 = assign[g * K_SZ + 2], a3 = assign[g * K_SZ + 3];
    float mx = fmaxf(fmaxf(a0, a1), fmaxf(a2, a3));
    const float L2E = 1.44269504f;
    float e0 = exp2f((a0 - mx) * L2E), e1 = exp2f((a1 - mx) * L2E);
    float e2 = exp2f((a2 - mx) * L2E), e3 = exp2f((a3 - mx) * L2E);
    float inv = 1.f / (e0 + e1 + e2 + e3);
    float r = e0 * inv * (o[0] / L[0]) + e1 * inv * (o[1] / L[1])
            + e2 * inv * (o[2] / L[2]) + e3 * inv * (o[3] / L[3]);
    out[(size_t)b * VA + va] = r;
}

extern "C" void kernel_launch(void* const* d_in, const int* in_sizes, int n_in,
                              void* d_out, int out_size, void* d_ws, size_t ws_size,
                              hipStream_t stream)
{
    const float* state  = (const float*)d_in[0];
    const float* hist   = (const float*)d_in[1];
    const float* act    = (const float*)d_in[2];
    const float* W0     = (const float*)d_in[3];
    const float* b0     = (const float*)d_in[4];
    const float* W1     = (const float*)d_in[5];
    const float* b1     = (const float*)d_in[6];
    const float* W2     = (const float*)d_in[7];
    const float* b2     = (const float*)d_in[8];
    const float* assign = (const float*)d_in[9];
    float* out = (float*)d_out;

    char* ws = (char*)d_ws;
    short* enc_s_h = (short*)(ws);                    //   524288 B
    short* enc_s_l = (short*)(ws + 524288);           //   524288 B
    short* kf_h    = (short*)(ws + 1048576);          //  8388608 B (2048 tiles x 4KB)
    short* kf_l    = (short*)(ws + 9437184);          //  8388608 B
    short* vf_h    = (short*)(ws + 17825792);         //  2621440 B (512 tiles x 5KB)
    short* vf_l    = (short*)(ws + 20447232);         //  2621440 B
    const size_t base = 23068672;

    float* Pm   = (float*)(ws + base);                           // 262144 B
    float* Pl   = (float*)(ws + base + 262144);                  // 262144 B
    float* Pacc = (float*)(ws + base + 524288);                  // 20971520 B
    char*  wt   = ws + base + 524288 + 20971520;                 // 163840 B
    short* w0fh = (short*)(wt);            // 16384 B
    short* w0fl = (short*)(wt + 16384);    // 16384 B
    short* w1fh = (short*)(wt + 32768);    // 32768 B
    short* w1fl = (short*)(wt + 65536);    // 32768 B
    short* w2fh = (short*)(wt + 98304);    // 32768 B
    short* w2fl = (short*)(wt + 131072);   // 32768 B
    // total = 44,728,320 B (~42.7 MiB)

    k_prep<<<160, 256, 0, stream>>>(W0, W1, W2, w0fh, w0fl, w1fh, w1fl, w2fh, w2fl);
    k_encode<<<1344, 256, 0, stream>>>(state, hist, act,
                                       w0fh, w0fl, w1fh, w1fl, w2fh, w2fl,
                                       b0, b1, b2,
                                       enc_s_h, enc_s_l, kf_h, kf_l, vf_h, vf_l);
    k_flash<NC><<<4096, 64, 0, stream>>>(enc_s_h, enc_s_l, kf_h, kf_l,
                                         vf_h, vf_l, Pm, Pl, Pacc);
    k_reduce<<<320, 256, 0, stream>>>(Pm, Pl, Pacc, assign, out);
}

// Round 11
// 151.783 us; speedup vs baseline: 1.1708x; 1.1708x over previous
//
#include <hip/hip_runtime.h>
#include <stdint.h>

#define B_SZ 1024
#define H_SZ 16384
#define SD   32
#define HID  64
#define G_SZ 10
#define K_SZ 4
#define A_SZ 8
#define VA   80         // G*A
#define NC   16         // chunks (Pacc = 21 MB; 512 flash blocks)

typedef float f32x4  __attribute__((ext_vector_type(4)));
typedef short bf16x8 __attribute__((ext_vector_type(8)));

__device__ inline short f2bf(float a) {
    unsigned u = __float_as_uint(a);
    return (short)((u + 0x7FFFu + ((u >> 16) & 1u)) >> 16);
}
__device__ inline void split_bf(float v, short& hi, short& lo) {
    hi = f2bf(v);
    lo = f2bf(v - __uint_as_float(((unsigned)(unsigned short)hi) << 16));
}
// HW packed f32->bf16 (RTNE — bit-identical to the manual pack, 1 instr).
__device__ inline int cvt_pk_bf16(float a, float b) {
    int r;
    asm("v_cvt_pk_bf16_f32 %0, %1, %2" : "=v"(r) : "v"(a), "v"(b));
    return r;
}
// hi/lo split of a PAIR via cvt_pk: bit-identical to split_bf elementwise.
__device__ inline void split2(float f0, float f1, int& hi, int& lo) {
    hi = cvt_pk_bf16(f0, f1);
    float r0 = f0 - __uint_as_float((unsigned)hi << 16);
    float r1 = f1 - __uint_as_float((unsigned)hi & 0xFFFF0000u);
    lo = cvt_pk_bf16(r0, r1);
}

// ---------------------------------------------------------------------------
// Kernel 0: pre-split weights to bf16 hi/lo in MFMA-FRAGMENT order.
// ---------------------------------------------------------------------------
__global__ __launch_bounds__(256) void k_prep(
    const float* __restrict__ W0, const float* __restrict__ W1,
    const float* __restrict__ W2,
    short* __restrict__ w0h, short* __restrict__ w0l,
    short* __restrict__ w1h, short* __restrict__ w1l,
    short* __restrict__ w2h, short* __restrict__ w2l)
{
    int idx = blockIdx.x * 256 + threadIdx.x;    // 40960 total
    short hh, ll;
    if (idx < 8192) {                            // w0f
        int k = idx >> 11, r = idx & 2047;
        int i = r >> 6, jj = r & 63;
        int tt = jj >> 4, l15 = jj & 15;
        int quad = (i >> 3) & 3, e = i & 7;
        split_bf(W0[k * 2048 + i * 64 + jj], hh, ll);
        int dst = k * 2048 + tt * 512 + (quad * 16 + l15) * 8 + e;
        w0h[dst] = hh; w0l[dst] = ll;
    } else if (idx < 24576) {                    // w1f
        int d = idx - 8192;
        int k = d >> 12, r = d & 4095;
        int i = r >> 6, jj = r & 63;
        int kb = i >> 5, quad = (i >> 3) & 3, e = i & 7;
        int tt = jj >> 4, l15 = jj & 15;
        split_bf(W1[k * 4096 + i * 64 + jj], hh, ll);
        int dst = k * 4096 + tt * 1024 + kb * 512 + (quad * 16 + l15) * 8 + e;
        w1h[dst] = hh; w1l[dst] = ll;
    } else if (idx < 40960) {                    // w2f
        int d = idx - 24576;
        int k = d >> 12, r = d & 4095;
        int i = r >> 6, jj = r & 63;
        int kb = i >> 5, quad = (i >> 3) & 3, e = i & 7;
        int tt = jj >> 4, l15 = jj & 15;
        split_bf(W2[k * 4096 + i * 64 + jj], hh, ll);
        int dst = k * 4096 + tt * 1024 + kb * 512 + (quad * 16 + l15) * 8 + e;
        w2h[dst] = hh; w2l[dst] = ll;
    }
}

// ---------------------------------------------------------------------------
// Kernel 1: per-k 3-layer MLP encoders (R8 structure).
// V-transpose role now writes Vf in SIGMA-PERMUTED fragment order so that
// k_flash's P (QK output) is a valid PV B-operand with ZERO cross-lane ops:
//   sigma(quad,e) = e<4 ? 4*quad+e : 16+4*quad+(e-4)
//   element (va, h within 32-tile): lane = ((h>>2)&3)*16 + (va&15),
//   slot e' = (h&3) + 4*((h>>4)&1).  MFMA sums over k, so permuting BOTH
//   A (V) and B (P) k-slots by sigma leaves the result unchanged.
// ---------------------------------------------------------------------------
__global__ __launch_bounds__(256, 3) void k_encode(
    const float* __restrict__ state, const float* __restrict__ hist,
    const float* __restrict__ act,
    const short* __restrict__ w0fh, const short* __restrict__ w0fl,
    const short* __restrict__ w1fh, const short* __restrict__ w1fl,
    const short* __restrict__ w2fh, const short* __restrict__ w2fl,
    const float* __restrict__ b0, const float* __restrict__ b1,
    const float* __restrict__ b2,
    short* __restrict__ enc_s_h, short* __restrict__ enc_s_l,
    short* __restrict__ kf_h, short* __restrict__ kf_l,
    short* __restrict__ vf_h, short* __restrict__ vf_l)
{
    __shared__ __align__(16) short smem[18432];   // 36864 B
    const int bid = blockIdx.x;
    const int t = threadIdx.x;

    if (bid >= 1088) {
        // ---- V transpose role: tile of 64 h rows ----
        short* tile_h = smem;                 // [64][84]
        short* tile_l = smem + 5376;
        const int h0 = (bid - 1088) * 64;
        #pragma unroll
        for (int i = 0; i < 10; ++i) {
            int idx2 = 2 * (t + i * 256);     // 0..5118, even
            float2 v = *(const float2*)(act + (size_t)h0 * VA + idx2);
            int h = idx2 / 80, c = idx2 - h * 80;
            int hi, lo; split2(v.x, v.y, hi, lo);
            *(int*)(tile_h + h * 84 + c) = hi;
            *(int*)(tile_l + h * 84 + c) = lo;
        }
        __syncthreads();
        #pragma unroll
        for (int i = 0; i < 3; ++i) {
            int jj = t + i * 256;             // 0..639 used
            if (jj < 640) {
                int va = jj >> 3, hb = jj & 7;
                union { short s[8]; uint2 d[2]; } uh, ul;
                #pragma unroll
                for (int uu = 0; uu < 8; ++uu) {
                    uh.s[uu] = tile_h[(hb * 8 + uu) * 84 + va];
                    ul.s[uu] = tile_l[(hb * 8 + uu) * 84 + va];
                }
                // sigma-permuted Vf layout (h_local = (hb&3)*8 + uu)
                int vtile = (h0 >> 5) + (hb >> 2);
                int H  = (hb >> 1) & 1;                 // (h_local>>4)&1
                int qa = (hb * 2) & 3;                  // (h_local>>2)&3, uu 0-3
                int qb = (hb * 2 + 1) & 3;              // uu 4-7
                size_t basev = (size_t)vtile * 2560 + (va >> 4) * 512;
                size_t aA = basev + (size_t)(qa * 16 + (va & 15)) * 8 + 4 * H;
                size_t aB = basev + (size_t)(qb * 16 + (va & 15)) * 8 + 4 * H;
                *(uint2*)(vf_h + aA) = uh.d[0];
                *(uint2*)(vf_h + aB) = uh.d[1];
                *(uint2*)(vf_l + aA) = ul.d[0];
                *(uint2*)(vf_l + aB) = ul.d[1];
            }
        }
        return;
    }

    // ---- encode role ----
    const int k = bid / 272;
    const int tl = bid % 272;
    const bool is_state = (tl < 16);
    const float qscale = is_state ? 1.44269504f : 1.0f;   // log2(e) into Q
    const float* X = is_state ? state + (size_t)tl * 64 * SD
                              : hist + (size_t)(tl - 16) * 64 * SD;
    short* dst_h = enc_s_h + ((size_t)k * B_SZ + tl * 64) * HID;
    short* dst_l = enc_s_l + ((size_t)k * B_SZ + tl * 64) * HID;

    // LDS (shorts), lifetime reuse: R1 = xt -> hb2, R2 = hb1 -> ot.
    short* xt_h  = smem;            // [64][40]
    short* xt_l  = smem + 2560;
    short* hb2_h = smem;            // [64][72] (L2 out, L3 in)
    short* hb2_l = smem + 4608;
    short* hb1_h = smem + 9216;     // [64][72] (L1 out, L2 in)
    short* hb1_l = smem + 13824;
    short* ot_h  = smem + 9216;     // L3 out staging (hb1 dead)
    short* ot_l  = smem + 13824;

    { // stage x tile (64x32 fp32 -> hi/lo), pairwise
        int r = t >> 2, c0 = (t & 3) * 8;
        const float* src = X + r * SD + c0;
        #pragma unroll
        for (int u = 0; u < 4; ++u) {
            float2 v = *(const float2*)(src + 2 * u);
            int hi, lo; split2(v.x, v.y, hi, lo);
            *(int*)(xt_h + r * 40 + c0 + 2 * u) = hi;
            *(int*)(xt_l + r * 40 + c0 + 2 * u) = lo;
        }
    }
    __syncthreads();

    const int w = t >> 6, l15 = t & 15, quad = (t >> 4) & 3, lane = t & 63;
    const f32x4 fz = {0.f, 0.f, 0.f, 0.f};
    const int row0 = w * 16 + quad * 4;

    // Layer 1 (K=32)
    {
        bf16x8 xa_h = *(const bf16x8*)(xt_h + (w * 16 + l15) * 40 + quad * 8);
        bf16x8 xa_l = *(const bf16x8*)(xt_l + (w * 16 + l15) * 40 + quad * 8);
        const float* b0k = b0 + k * HID;
        const short* wbh = w0fh + k * 2048 + lane * 8;
        const short* wbl = w0fl + k * 2048 + lane * 8;
        #pragma unroll
        for (int tt = 0; tt < 4; ++tt) {
            bf16x8 wf_h = *(const bf16x8*)(wbh + tt * 512);
            bf16x8 wf_l = *(const bf16x8*)(wbl + tt * 512);
            f32x4 c = __builtin_amdgcn_mfma_f32_16x16x32_bf16(xa_h, wf_h, fz, 0, 0, 0);
            c = __builtin_amdgcn_mfma_f32_16x16x32_bf16(xa_l, wf_h, c, 0, 0, 0);
            c = __builtin_amdgcn_mfma_f32_16x16x32_bf16(xa_h, wf_l, c, 0, 0, 0);
            float bias = b0k[l15 + 16 * tt];
            float f0 = fmaxf(c[0] + bias, 0.f), f1 = fmaxf(c[1] + bias, 0.f);
            float f2 = fmaxf(c[2] + bias, 0.f), f3 = fmaxf(c[3] + bias, 0.f);
            int h01, l01, h23, l23;
            split2(f0, f1, h01, l01); split2(f2, f3, h23, l23);
            int cc = l15 + 16 * tt;
            hb1_h[(row0    ) * 72 + cc] = (short)h01;
            hb1_h[(row0 + 1) * 72 + cc] = (short)(h01 >> 16);
            hb1_h[(row0 + 2) * 72 + cc] = (short)h23;
            hb1_h[(row0 + 3) * 72 + cc] = (short)(h23 >> 16);
            hb1_l[(row0    ) * 72 + cc] = (short)l01;
            hb1_l[(row0 + 1) * 72 + cc] = (short)(l01 >> 16);
            hb1_l[(row0 + 2) * 72 + cc] = (short)l23;
            hb1_l[(row0 + 3) * 72 + cc] = (short)(l23 >> 16);
        }
    }
    __syncthreads();
    // Layer 2 (K=64)
    {
        bf16x8 ha0_h = *(const bf16x8*)(hb1_h + (w * 16 + l15) * 72 + quad * 8);
        bf16x8 ha0_l = *(const bf16x8*)(hb1_l + (w * 16 + l15) * 72 + quad * 8);
        bf16x8 ha1_h = *(const bf16x8*)(hb1_h + (w * 16 + l15) * 72 + 32 + quad * 8);
        bf16x8 ha1_l = *(const bf16x8*)(hb1_l + (w * 16 + l15) * 72 + 32 + quad * 8);
        const float* b1k = b1 + k * HID;
        const short* wbh = w1fh + k * 4096 + lane * 8;
        const short* wbl = w1fl + k * 4096 + lane * 8;
        #pragma unroll
        for (int tt = 0; tt < 4; ++tt) {
            bf16x8 wfa_h = *(const bf16x8*)(wbh + tt * 1024);
            bf16x8 wfb_h = *(const bf16x8*)(wbh + tt * 1024 + 512);
            bf16x8 wfa_l = *(const bf16x8*)(wbl + tt * 1024);
            bf16x8 wfb_l = *(const bf16x8*)(wbl + tt * 1024 + 512);
            f32x4 c = __builtin_amdgcn_mfma_f32_16x16x32_bf16(ha0_h, wfa_h, fz, 0, 0, 0);
            c = __builtin_amdgcn_mfma_f32_16x16x32_bf16(ha1_h, wfb_h, c, 0, 0, 0);
            c = __builtin_amdgcn_mfma_f32_16x16x32_bf16(ha0_l, wfa_h, c, 0, 0, 0);
            c = __builtin_amdgcn_mfma_f32_16x16x32_bf16(ha1_l, wfb_h, c, 0, 0, 0);
            c = __builtin_amdgcn_mfma_f32_16x16x32_bf16(ha0_h, wfa_l, c, 0, 0, 0);
            c = __builtin_amdgcn_mfma_f32_16x16x32_bf16(ha1_h, wfb_l, c, 0, 0, 0);
            float bias = b1k[l15 + 16 * tt];
            float f0 = fmaxf(c[0] + bias, 0.f), f1 = fmaxf(c[1] + bias, 0.f);
            float f2 = fmaxf(c[2] + bias, 0.f), f3 = fmaxf(c[3] + bias, 0.f);
            int h01, l01, h23, l23;
            split2(f0, f1, h01, l01); split2(f2, f3, h23, l23);
            int cc = l15 + 16 * tt;
            hb2_h[(row0    ) * 72 + cc] = (short)h01;
            hb2_h[(row0 + 1) * 72 + cc] = (short)(h01 >> 16);
            hb2_h[(row0 + 2) * 72 + cc] = (short)h23;
            hb2_h[(row0 + 3) * 72 + cc] = (short)(h23 >> 16);
            hb2_l[(row0    ) * 72 + cc] = (short)l01;
            hb2_l[(row0 + 1) * 72 + cc] = (short)(l01 >> 16);
            hb2_l[(row0 + 2) * 72 + cc] = (short)l23;
            hb2_l[(row0 + 3) * 72 + cc] = (short)(l23 >> 16);
        }
    }
    __syncthreads();
    // Layer 3 (K=64): hb2 -> ot
    {
        bf16x8 ha0_h = *(const bf16x8*)(hb2_h + (w * 16 + l15) * 72 + quad * 8);
        bf16x8 ha0_l = *(const bf16x8*)(hb2_l + (w * 16 + l15) * 72 + quad * 8);
        bf16x8 ha1_h = *(const bf16x8*)(hb2_h + (w * 16 + l15) * 72 + 32 + quad * 8);
        bf16x8 ha1_l = *(const bf16x8*)(hb2_l + (w * 16 + l15) * 72 + 32 + quad * 8);
        const float* b2k = b2 + k * HID;
        const short* wbh = w2fh + k * 4096 + lane * 8;
        const short* wbl = w2fl + k * 4096 + lane * 8;
        #pragma unroll
        for (int tt = 0; tt < 4; ++tt) {
            bf16x8 wfa_h = *(const bf16x8*)(wbh + tt * 1024);
            bf16x8 wfb_h = *(const bf16x8*)(wbh + tt * 1024 + 512);
            bf16x8 wfa_l = *(const bf16x8*)(wbl + tt * 1024);
            bf16x8 wfb_l = *(const bf16x8*)(wbl + tt * 1024 + 512);
            f32x4 c = __builtin_amdgcn_mfma_f32_16x16x32_bf16(ha0_h, wfa_h, fz, 0, 0, 0);
            c = __builtin_amdgcn_mfma_f32_16x16x32_bf16(ha1_h, wfb_h, c, 0, 0, 0);
            c = __builtin_amdgcn_mfma_f32_16x16x32_bf16(ha0_l, wfa_h, c, 0, 0, 0);
            c = __builtin_amdgcn_mfma_f32_16x16x32_bf16(ha1_l, wfb_h, c, 0, 0, 0);
            c = __builtin_amdgcn_mfma_f32_16x16x32_bf16(ha0_h, wfa_l, c, 0, 0, 0);
            c = __builtin_amdgcn_mfma_f32_16x16x32_bf16(ha1_h, wfb_l, c, 0, 0, 0);
            float bias = b2k[l15 + 16 * tt];
            float f0 = fmaxf(c[0] + bias, 0.f) * qscale;
            float f1 = fmaxf(c[1] + bias, 0.f) * qscale;
            float f2 = fmaxf(c[2] + bias, 0.f) * qscale;
            float f3 = fmaxf(c[3] + bias, 0.f) * qscale;
            int h01, l01, h23, l23;
            split2(f0, f1, h01, l01); split2(f2, f3, h23, l23);
            int cc = l15 + 16 * tt;
            ot_h[(row0    ) * 72 + cc] = (short)h01;
            ot_h[(row0 + 1) * 72 + cc] = (short)(h01 >> 16);
            ot_h[(row0 + 2) * 72 + cc] = (short)h23;
            ot_h[(row0 + 3) * 72 + cc] = (short)(h23 >> 16);
            ot_l[(row0    ) * 72 + cc] = (short)l01;
            ot_l[(row0 + 1) * 72 + cc] = (short)(l01 >> 16);
            ot_l[(row0 + 2) * 72 + cc] = (short)l23;
            ot_l[(row0 + 3) * 72 + cc] = (short)(l23 >> 16);
        }
    }
    __syncthreads();
    // Coalesced global write: 512 uint4-pairs, 2 per thread.
    if (is_state) {
        #pragma unroll
        for (int u = 0; u < 2; ++u) {
            int id = t * 2 + u;               // 0..511
            int row = id >> 3, c0 = (id & 7) * 8;
            *(uint4*)(dst_h + row * HID + c0) = *(const uint4*)(ot_h + row * 72 + c0);
            *(uint4*)(dst_l + row * HID + c0) = *(const uint4*)(ot_l + row * 72 + c0);
        }
    } else {
        const int ktbase = k * 512 + (tl - 16) * 2;
        #pragma unroll
        for (int u = 0; u < 2; ++u) {
            int id = t * 2 + u;               // 0..511
            int kt2 = id >> 8;                // 0..1
            int f2 = (id >> 6) & 3;
            int lanep = id & 63;
            int hl = kt2 * 32 + ((f2 >> 1) & 1) * 16 + (lanep & 15);
            int c0 = (f2 & 1) * 32 + ((lanep >> 4) & 3) * 8;
            size_t a = (size_t)(ktbase + kt2) * 2048 + f2 * 512 + (size_t)lanep * 8;
            *(uint4*)(kf_h + a) = *(const uint4*)(ot_h + hl * 72 + c0);
            *(uint4*)(kf_l + a) = *(const uint4*)(ot_l + hl * 72 + c0);
        }
    }
}

// ---------------------------------------------------------------------------
// Kernel 2: flash attention partials — R9 256-thread register-pipeline base
// (proven 70 µs), with ZERO-SHUFFLE softmax: Vf is sigma-permuted, so
// pfv = {pk(p0,p1),pk(p2,p3),pk(p4,p5),pk(p6,p7)} feeds PV directly.
// Deletes 16 of 24 LDS-pipe (ds_bpermute) ops per wave-iter — the shared
// per-CU resource that R8-vs-R9 occupancy invariance implicated.
// ---------------------------------------------------------------------------
template<int NCt>
__global__ __launch_bounds__(256, 2) void k_flash(
    const short* __restrict__ enc_s_h, const short* __restrict__ enc_s_l,
    const short* __restrict__ kf_h, const short* __restrict__ kf_l,
    const short* __restrict__ vf_h, const short* __restrict__ vf_l,
    float* __restrict__ Pm, float* __restrict__ Pl, float* __restrict__ Pacc)
{
    constexpr int CHt = H_SZ / NCt;
    constexpr int NT = CHt / 32;
    static_assert(NT % 2 == 0, "NT must be even for 2x unroll");

    const int bid = blockIdx.x;
    const int r8 = bid & 7, j = bid >> 3;
    const int mtile = j & 7, grp = j >> 3;
    const int idx = grp * 8 + r8;
    const int k = idx / NCt, chunk = idx % NCt;
    const int t = threadIdx.x, w = t >> 6, lane = t & 63;
    const int l15 = t & 15, quad = (t >> 4) & 3;
    const int q0 = mtile * 128 + w * 32;
    const f32x4 fz = {0.f, 0.f, 0.f, 0.f};

    bf16x8 qh[2][2], ql[2][2];
    #pragma unroll
    for (int sub = 0; sub < 2; ++sub)
        #pragma unroll
        for (int kb = 0; kb < 2; ++kb) {
            size_t off = ((size_t)k * B_SZ + q0 + sub * 16 + l15) * HID + kb * 32 + quad * 8;
            qh[sub][kb] = *(const bf16x8*)(enc_s_h + off);
            ql[sub][kb] = *(const bf16x8*)(enc_s_l + off);
        }

    f32x4 acc[2][5];
    #pragma unroll
    for (int s = 0; s < 2; ++s)
        #pragma unroll
        for (int tt = 0; tt < 5; ++tt) acc[s][tt] = fz;
    float mrun[2] = {-__builtin_inff(), -__builtin_inff()};
    float lrun[2] = {0.f, 0.f};

    const int tile0 = chunk * NT;
    const short* kbh = kf_h + ((size_t)(k * 512 + tile0)) * 2048 + lane * 8;
    const short* kbl = kf_l + ((size_t)(k * 512 + tile0)) * 2048 + lane * 8;
    const short* vbh = vf_h + (size_t)tile0 * 2560 + lane * 8;
    const short* vbl = vf_l + (size_t)tile0 * 2560 + lane * 8;

    bf16x8 kA[8], kB[8];
    #pragma unroll
    for (int f = 0; f < 4; ++f) {
        kA[f]     = *(const bf16x8*)(kbh + f * 512);
        kA[4 + f] = *(const bf16x8*)(kbl + f * 512);
    }

    auto body = [&](bf16x8 (&kc)[8], bf16x8 (&kn)[8], int it) {
        bf16x8 vh[5], vl[5];
        const short* vph = vbh + (size_t)it * 2560;
        const short* vpl = vbl + (size_t)it * 2560;
        #pragma unroll
        for (int tt = 0; tt < 3; ++tt) {
            vh[tt] = *(const bf16x8*)(vph + tt * 512);
            vl[tt] = *(const bf16x8*)(vpl + tt * 512);
        }
        if (it + 1 < NT) {
            const short* nph = kbh + (size_t)(it + 1) * 2048;
            const short* npl = kbl + (size_t)(it + 1) * 2048;
            #pragma unroll
            for (int f = 0; f < 4; ++f) {
                kn[f]     = *(const bf16x8*)(nph + f * 512);
                kn[4 + f] = *(const bf16x8*)(npl + f * 512);
            }
        }

        f32x4 S[2][2];
        __builtin_amdgcn_s_setprio(1);
        #pragma unroll
        for (int sub = 0; sub < 2; ++sub) {
            f32x4 c = __builtin_amdgcn_mfma_f32_16x16x32_bf16(kc[0], qh[sub][0], fz, 0, 0, 0);
            c = __builtin_amdgcn_mfma_f32_16x16x32_bf16(kc[1], qh[sub][1], c, 0, 0, 0);
            c = __builtin_amdgcn_mfma_f32_16x16x32_bf16(kc[4], qh[sub][0], c, 0, 0, 0);
            c = __builtin_amdgcn_mfma_f32_16x16x32_bf16(kc[5], qh[sub][1], c, 0, 0, 0);
            c = __builtin_amdgcn_mfma_f32_16x16x32_bf16(kc[0], ql[sub][0], c, 0, 0, 0);
            c = __builtin_amdgcn_mfma_f32_16x16x32_bf16(kc[1], ql[sub][1], c, 0, 0, 0);
            S[sub][0] = c;
            f32x4 d = __builtin_amdgcn_mfma_f32_16x16x32_bf16(kc[2], qh[sub][0], fz, 0, 0, 0);
            d = __builtin_amdgcn_mfma_f32_16x16x32_bf16(kc[3], qh[sub][1], d, 0, 0, 0);
            d = __builtin_amdgcn_mfma_f32_16x16x32_bf16(kc[6], qh[sub][0], d, 0, 0, 0);
            d = __builtin_amdgcn_mfma_f32_16x16x32_bf16(kc[7], qh[sub][1], d, 0, 0, 0);
            d = __builtin_amdgcn_mfma_f32_16x16x32_bf16(kc[2], ql[sub][0], d, 0, 0, 0);
            d = __builtin_amdgcn_mfma_f32_16x16x32_bf16(kc[3], ql[sub][1], d, 0, 0, 0);
            S[sub][1] = d;
        }
        __builtin_amdgcn_s_setprio(0);

        #pragma unroll
        for (int tt = 3; tt < 5; ++tt) {
            vh[tt] = *(const bf16x8*)(vph + tt * 512);
            vl[tt] = *(const bf16x8*)(vpl + tt * 512);
        }

        bf16x8 pfv[2];
        #pragma unroll
        for (int sub = 0; sub < 2; ++sub) {
            f32x4 slo = S[sub][0], shi = S[sub][1];
            float a3 = fmaxf(fmaxf(slo[0], slo[1]), slo[2]);
            float b3 = fmaxf(fmaxf(slo[3], shi[0]), shi[1]);
            float c3 = fmaxf(fmaxf(shi[2], shi[3]), a3);
            float tm = fmaxf(b3, c3);
            tm = fmaxf(tm, __shfl_xor(tm, 16));
            tm = fmaxf(tm, __shfl_xor(tm, 32));
            if (__any(tm > mrun[sub])) {
                float mnew = fmaxf(mrun[sub], tm);
                float alpha = exp2f(mrun[sub] - mnew);
                lrun[sub] *= alpha;
                #pragma unroll
                for (int tt = 0; tt < 5; ++tt) acc[sub][tt] = acc[sub][tt] * alpha;
                mrun[sub] = mnew;
            }
            float m = mrun[sub];
            float p0 = exp2f(slo[0] - m), p1 = exp2f(slo[1] - m);
            float p2 = exp2f(slo[2] - m), p3 = exp2f(slo[3] - m);
            float p4 = exp2f(shi[0] - m), p5 = exp2f(shi[1] - m);
            float p6 = exp2f(shi[2] - m), p7 = exp2f(shi[3] - m);
            float ps = (p0 + p1) + (p2 + p3) + (p4 + p5) + (p6 + p7);
            ps += __shfl_xor(ps, 16);
            ps += __shfl_xor(ps, 32);
            lrun[sub] += ps;

            // Zero-shuffle P fragment: sigma-permuted V matches this order.
            union { int i[4]; bf16x8 v; } pf;
            pf.i[0] = cvt_pk_bf16(p0, p1);
            pf.i[1] = cvt_pk_bf16(p2, p3);
            pf.i[2] = cvt_pk_bf16(p4, p5);
            pf.i[3] = cvt_pk_bf16(p6, p7);
            pfv[sub] = pf.v;
        }

        __builtin_amdgcn_s_setprio(1);
        #pragma unroll
        for (int tt = 0; tt < 5; ++tt) {
            acc[0][tt] = __builtin_amdgcn_mfma_f32_16x16x32_bf16(vh[tt], pfv[0], acc[0][tt], 0, 0, 0);
            acc[0][tt] = __builtin_amdgcn_mfma_f32_16x16x32_bf16(vl[tt], pfv[0], acc[0][tt], 0, 0, 0);
            acc[1][tt] = __builtin_amdgcn_mfma_f32_16x16x32_bf16(vh[tt], pfv[1], acc[1][tt], 0, 0, 0);
            acc[1][tt] = __builtin_amdgcn_mfma_f32_16x16x32_bf16(vl[tt], pfv[1], acc[1][tt], 0, 0, 0);
        }
        __builtin_amdgcn_s_setprio(0);
    };

    for (int ii = 0; ii < NT; ii += 2) {
        body(kA, kB, ii);
        body(kB, kA, ii + 1);
    }

    const int qg = k * B_SZ + q0;
    #pragma unroll
    for (int sub = 0; sub < 2; ++sub) {
        int q = qg + sub * 16 + l15;
        if (quad == 0) {
            Pm[chunk * 4096 + q] = mrun[sub];
            Pl[chunk * 4096 + q] = lrun[sub];
        }
        #pragma unroll
        for (int tt = 0; tt < 5; ++tt)
            #pragma unroll
            for (int r = 0; r < 4; ++r) {
                int va = tt * 16 + quad * 4 + r;
                Pacc[((size_t)chunk * VA + va) * 4096 + q] = acc[sub][tt][r];
            }
    }
}

// ---------------------------------------------------------------------------
// Kernel 3: FUSED combine (R9 version, unchanged): per thread one (b,va),
// all 4 k's combined + softmax(assignment) mix.
// ---------------------------------------------------------------------------
__global__ __launch_bounds__(256) void k_reduce(
    const float* __restrict__ Pm, const float* __restrict__ Pl,
    const float* __restrict__ Pacc, const float* __restrict__ assign,
    float* __restrict__ out)
{
    const int bid = blockIdx.x;
    const int qb = bid / 20, vcg = bid - qb * 20;
    const int t = threadIdx.x;
    const int b = qb * 64 + (t & 63);
    const int va = vcg * 4 + (t >> 6);
    const int g = va >> 3;

    float mc[K_SZ][NC];
    float M[K_SZ] = {-__builtin_inff(), -__builtin_inff(),
                     -__builtin_inff(), -__builtin_inff()};
    #pragma unroll
    for (int c = 0; c < NC; ++c)
        #pragma unroll
        for (int k = 0; k < K_SZ; ++k) {
            float m = Pm[c * 4096 + k * B_SZ + b];
            mc[k][c] = m;
            M[k] = fmaxf(M[k], m);
        }
    float L[K_SZ] = {0.f, 0.f, 0.f, 0.f};
    #pragma unroll
    for (int c = 0; c < NC; ++c)
        #pragma unroll
        for (int k = 0; k < K_SZ; ++k) {
            float wv = exp2f(mc[k][c] - M[k]);
            mc[k][c] = wv;
            L[k] += wv * Pl[c * 4096 + k * B_SZ + b];
        }
    float o[K_SZ] = {0.f, 0.f, 0.f, 0.f};
    #pragma unroll
    for (int c = 0; c < NC; ++c)
        #pragma unroll
        for (int k = 0; k < K_SZ; ++k)
            o[k] += mc[k][c] * Pacc[((size_t)(c * VA + va)) * 4096 + k * B_SZ + b];

    float a0 = assign[g * K_SZ + 0], a1 = assign[g * K_SZ + 1];
    float a2 = assign[g * K_SZ + 2], a3 = assign[g * K_SZ + 3];
    float mx = fmaxf(fmaxf(a0, a1), fmaxf(a2, a3));
    const float L2E = 1.44269504f;
    float e0 = exp2f((a0 - mx) * L2E), e1 = exp2f((a1 - mx) * L2E);
    float e2 = exp2f((a2 - mx) * L2E), e3 = exp2f((a3 - mx) * L2E);
    float inv = 1.f / (e0 + e1 + e2 + e3);
    float r = e0 * inv * (o[0] / L[0]) + e1 * inv * (o[1] / L[1])
            + e2 * inv * (o[2] / L[2]) + e3 * inv * (o[3] / L[3]);
    out[(size_t)b * VA + va] = r;
}

extern "C" void kernel_launch(void* const* d_in, const int* in_sizes, int n_in,
                              void* d_out, int out_size, void* d_ws, size_t ws_size,
                              hipStream_t stream)
{
    const float* state  = (const float*)d_in[0];
    const float* hist   = (const float*)d_in[1];
    const float* act    = (const float*)d_in[2];
    const float* W0     = (const float*)d_in[3];
    const float* b0     = (const float*)d_in[4];
    const float* W1     = (const float*)d_in[5];
    const float* b1     = (const float*)d_in[6];
    const float* W2     = (const float*)d_in[7];
    const float* b2     = (const float*)d_in[8];
    const float* assign = (const float*)d_in[9];
    float* out = (float*)d_out;

    char* ws = (char*)d_ws;
    short* enc_s_h = (short*)(ws);                    //   524288 B
    short* enc_s_l = (short*)(ws + 524288);           //   524288 B
    short* kf_h    = (short*)(ws + 1048576);          //  8388608 B (2048 tiles x 4KB)
    short* kf_l    = (short*)(ws + 9437184);          //  8388608 B
    short* vf_h    = (short*)(ws + 17825792);         //  2621440 B (512 tiles x 5KB)
    short* vf_l    = (short*)(ws + 20447232);         //  2621440 B
    const size_t base = 23068672;

    float* Pm   = (float*)(ws + base);                           // 262144 B
    float* Pl   = (float*)(ws + base + 262144);                  // 262144 B
    float* Pacc = (float*)(ws + base + 524288);                  // 20971520 B
    char*  wt   = ws + base + 524288 + 20971520;                 // 163840 B
    short* w0fh = (short*)(wt);            // 16384 B
    short* w0fl = (short*)(wt + 16384);    // 16384 B
    short* w1fh = (short*)(wt + 32768);    // 32768 B
    short* w1fl = (short*)(wt + 65536);    // 32768 B
    short* w2fh = (short*)(wt + 98304);    // 32768 B
    short* w2fl = (short*)(wt + 131072);   // 32768 B
    // total = 44,728,320 B (~42.7 MiB)

    k_prep<<<160, 256, 0, stream>>>(W0, W1, W2, w0fh, w0fl, w1fh, w1fl, w2fh, w2fl);
    k_encode<<<1344, 256, 0, stream>>>(state, hist, act,
                                       w0fh, w0fl, w1fh, w1fl, w2fh, w2fl,
                                       b0, b1, b2,
                                       enc_s_h, enc_s_l, kf_h, kf_l, vf_h, vf_l);
    k_flash<NC><<<512, 256, 0, stream>>>(enc_s_h, enc_s_l, kf_h, kf_l,
                                         vf_h, vf_l, Pm, Pl, Pacc);
    k_reduce<<<320, 256, 0, stream>>>(Pm, Pl, Pacc, assign, out);
}